// Round 1
// baseline (362.325 us; speedup 1.0000x reference)
//
#include <hip/hip_runtime.h>
#include <math.h>

constexpr int cH = 56, cW = 56, cC = 96, cDI = 192, cN = 16, cDR = 6, cK = 4, cMH = 384;
constexpr int cL = cH * cW;          // 3136
constexpr int cNC = 16;              // number of scan chunks
constexpr int cCH = cL / cNC;        // 196 chunk length
constexpr float LOG2E = 1.44269504088896340736f;

__device__ __forceinline__ float siluf(float x) { return x / (1.f + expf(-x)); }
__device__ __forceinline__ float geluf(float x) {
    float x3 = x * x * x;
    return 0.5f * x * (1.f + tanhf(0.7978845608028654f * (x + 0.044715f * x3)));
}

// ---------------- LayerNorm over 96 cols, one wave per row ----------------
__global__ void ln96_kernel(const float* __restrict__ x, const float* __restrict__ g,
                            const float* __restrict__ b, float* __restrict__ out, int M) {
    int wid = threadIdx.x >> 6;
    int lane = threadIdx.x & 63;
    int row = blockIdx.x * 4 + wid;
    if (row >= M) return;
    const float* xr = x + row * cC;
    float v0 = xr[lane];
    float v1 = (lane < cC - 64) ? xr[lane + 64] : 0.f;
    float s = v0 + v1;
    float sq = v0 * v0 + v1 * v1;
#pragma unroll
    for (int off = 32; off; off >>= 1) {
        s += __shfl_xor(s, off, 64);
        sq += __shfl_xor(sq, off, 64);
    }
    float m = s * (1.f / cC);
    float var = sq * (1.f / cC) - m * m;
    float rstd = rsqrtf(var + 1e-5f);
    out[row * cC + lane] = (v0 - m) * rstd * g[lane] + b[lane];
    if (lane < cC - 64)
        out[row * cC + lane + 64] = (v1 - m) * rstd * g[lane + 64] + b[lane + 64];
}

// ---------------- generic fp32 GEMM: C = A(MxK) @ B(KxN) [+bias][gelu][+res] --------
// block (64,4): each thread does 1 row x 2 cols
template <int ACT, bool HASB, bool HASR>
__global__ void gemm_kernel(const float* __restrict__ A, const float* __restrict__ B,
                            const float* __restrict__ bias, const float* __restrict__ res,
                            float* __restrict__ C, int M, int Nn, int Kk) {
    int c0 = blockIdx.x * 128 + threadIdx.x * 2;
    int row = blockIdx.y * 4 + threadIdx.y;
    if (row >= M || c0 >= Nn) return;
    const float* Ar = A + row * Kk;
    float a0 = 0.f, a1 = 0.f;
#pragma unroll 4
    for (int k = 0; k < Kk; k++) {
        float av = Ar[k];
        const float2 bv = *reinterpret_cast<const float2*>(B + (size_t)k * Nn + c0);
        a0 = fmaf(av, bv.x, a0);
        a1 = fmaf(av, bv.y, a1);
    }
    if (HASB) { a0 += bias[c0]; a1 += bias[c0 + 1]; }
    if (ACT == 1) { a0 = geluf(a0); a1 = geluf(a1); }
    if (HASR) { a0 += res[row * Nn + c0]; a1 += res[row * Nn + c0 + 1]; }
    C[row * Nn + c0] = a0;
    C[row * Nn + c0 + 1] = a1;
}

// ---------------- depthwise 3x3 conv + bias + silu ----------------
// input: first DI cols of xz (L x 2DI); output xconv (L x DI)
__global__ void conv_silu_kernel(const float* __restrict__ xz, const float* __restrict__ cw,
                                 const float* __restrict__ cb, float* __restrict__ out) {
    int idx = blockIdx.x * 256 + threadIdx.x;
    if (idx >= cL * cDI) return;
    int d = idx % cDI;
    int l = idx / cDI;
    int h = l / cW, w = l % cW;
    float s = cb[d];
#pragma unroll
    for (int dh = 0; dh < 3; dh++) {
        int hh = h + dh - 1;
        if (hh < 0 || hh >= cH) continue;
#pragma unroll
        for (int dw = 0; dw < 3; dw++) {
            int w2 = w + dw - 1;
            if (w2 < 0 || w2 >= cW) continue;
            s = fmaf(xz[(size_t)(hh * cW + w2) * (2 * cDI) + d], cw[(dh * 3 + dw) * cDI + d], s);
        }
    }
    out[idx] = siluf(s);
}

// ---------------- x_proj + dt_proj per (k, 16 physical positions) ----------------
// writes dt [K][DI][L], Bs [K][L][N], Cs [K][L][N] (all at PHYSICAL position)
__global__ void proj_kernel(const float* __restrict__ xconv, const float* __restrict__ xpw,
                            const float* __restrict__ dtw, const float* __restrict__ dtb,
                            float* __restrict__ dtout, float* __restrict__ Bsout,
                            float* __restrict__ Csout) {
    __shared__ float XS[16 * 193];
    __shared__ float DTS[6 * 16];
    int k = blockIdx.y;
    int p0 = blockIdx.x * 16;
    int tid = threadIdx.x;
    for (int idx = tid; idx < 16 * cDI; idx += 256) {
        int p = idx / cDI, d = idx % cDI;
        int pp = p0 + p;
        int rrow;
        if (k & 1) { int h = pp % cH, w = pp / cH; rrow = h * cW + w; }
        else rrow = pp;
        XS[p * 193 + d] = xconv[(size_t)rrow * cDI + d];
    }
    __syncthreads();
    for (int o = tid; o < 38 * 16; o += 256) {
        int c = o >> 4, p = o & 15;
        const float* wr = xpw + (size_t)(k * 38 + c) * cDI;
        const float* xr = XS + p * 193;
        float s = 0.f;
#pragma unroll 4
        for (int d = 0; d < cDI; d++) s = fmaf(wr[d], xr[d], s);
        if (c < 6) DTS[c * 16 + p] = s;
        else if (c < 22) Bsout[(size_t)(k * cL + p0 + p) * cN + (c - 6)] = s;
        else Csout[(size_t)(k * cL + p0 + p) * cN + (c - 22)] = s;
    }
    __syncthreads();
    for (int o = tid; o < cDI * 16; o += 256) {
        int d = o >> 4, p = o & 15;
        float s = dtb[k * cDI + d];
        const float* wr = dtw + (size_t)(k * cDI + d) * cDR;
#pragma unroll
        for (int r = 0; r < cDR; r++) s = fmaf(wr[r], DTS[r * 16 + p], s);
        float sp = (s > 20.f) ? s : log1pf(expf(s));
        dtout[(size_t)(k * cDI + d) * cL + p0 + p] = sp;
    }
}

// ---------------- scan pass 1: per-chunk local scan (h starts at 0) ----------------
// block 256 = 16 groups(d) x 16 lanes(n); block -> (k, d0..d0+15, chunk)
__global__ void scan1_kernel(const float* __restrict__ dtbuf, const float* __restrict__ Bs,
                             const float* __restrict__ xconv, const float* __restrict__ Alogs,
                             float* __restrict__ carryP, float* __restrict__ carryH) {
    int bx = blockIdx.x;
    int c = bx % cNC;
    int t2 = bx / cNC;
    int d0 = (t2 % (cDI / 16)) * 16;
    int k = t2 / (cDI / 16);
    int g = threadIdx.x >> 4;
    int n = threadIdx.x & 15;
    int d = d0 + g;
    int kd = k * cDI + d;
    float An = -expf(Alogs[kd * cN + n]);
    bool fwd = (k < 2);
    bool odd = (k & 1);
    int s0 = c * cCH;
    int hh = 0, ww = 0;
    if (odd) {
        int lc0 = fwd ? s0 : (cL - 1 - s0);
        hh = lc0 % cH;
        ww = lc0 / cH;
    }
    const float* dtp = dtbuf + (size_t)kd * cL;
    const float* bsp = Bs + (size_t)k * cL * cN + n;
    float h = 0.f, S = 0.f;
    for (int i = 0; i < cCH; i++) {
        int l = fwd ? (s0 + i) : (cL - 1 - s0 - i);
        float dt = dtp[l];
        int xr = odd ? (hh * cW + ww) : l;
        float xv = xconv[(size_t)xr * cDI + d];
        float bv = bsp[(size_t)l * cN];
        float a = exp2f(An * dt * LOG2E);
        h = fmaf(a, h, dt * bv * xv);
        S += dt;
        if (odd) {
            if (fwd) { hh++; if (hh == cH) { hh = 0; ww++; } }
            else { hh--; if (hh < 0) { hh = cH - 1; ww--; } }
        }
    }
    float P = exp2f(An * S * LOG2E);
    int idxc = (kd * cNC + c) * cN + n;
    carryH[idxc] = h;
    carryP[idxc] = P;
}

// ---------------- scan pass 2: sequential carry combine across chunks ----------------
__global__ void scan2_kernel(const float* __restrict__ carryP, const float* __restrict__ carryH,
                             float* __restrict__ hin) {
    int gid = blockIdx.x * 256 + threadIdx.x;
    if (gid >= cK * cDI * cN) return;
    int kd = gid / cN, n = gid % cN;
    float h = 0.f;
    for (int c = 0; c < cNC; c++) {
        int idxc = (kd * cNC + c) * cN + n;
        hin[idxc] = h;
        h = fmaf(carryP[idxc], h, carryH[idxc]);
    }
}

// ---------------- scan pass 3: local scan with carry seed + C-contraction ----------------
// writes ys [K][L][DI] at PHYSICAL position
__global__ void scan3_kernel(const float* __restrict__ dtbuf, const float* __restrict__ Bs,
                             const float* __restrict__ Cs, const float* __restrict__ xconv,
                             const float* __restrict__ Alogs, const float* __restrict__ Ds,
                             const float* __restrict__ hin, float* __restrict__ ys) {
    int bx = blockIdx.x;
    int c = bx % cNC;
    int t2 = bx / cNC;
    int d0 = (t2 % (cDI / 16)) * 16;
    int k = t2 / (cDI / 16);
    int g = threadIdx.x >> 4;
    int n = threadIdx.x & 15;
    int d = d0 + g;
    int kd = k * cDI + d;
    float An = -expf(Alogs[kd * cN + n]);
    float Dv = Ds[kd];
    bool fwd = (k < 2);
    bool odd = (k & 1);
    int s0 = c * cCH;
    int hh = 0, ww = 0;
    if (odd) {
        int lc0 = fwd ? s0 : (cL - 1 - s0);
        hh = lc0 % cH;
        ww = lc0 / cH;
    }
    const float* dtp = dtbuf + (size_t)kd * cL;
    const float* bsp = Bs + (size_t)k * cL * cN + n;
    const float* csp = Cs + (size_t)k * cL * cN + n;
    float h = hin[(kd * cNC + c) * cN + n];
    for (int i = 0; i < cCH; i++) {
        int l = fwd ? (s0 + i) : (cL - 1 - s0 - i);
        float dt = dtp[l];
        int xr = odd ? (hh * cW + ww) : l;
        float xv = xconv[(size_t)xr * cDI + d];
        float bv = bsp[(size_t)l * cN];
        float a = exp2f(An * dt * LOG2E);
        h = fmaf(a, h, dt * bv * xv);
        float t = h * csp[(size_t)l * cN];
        t += __shfl_xor(t, 8, 16);
        t += __shfl_xor(t, 4, 16);
        t += __shfl_xor(t, 2, 16);
        t += __shfl_xor(t, 1, 16);
        if (n == 0) ys[(size_t)(k * cL + l) * cDI + d] = t + Dv * xv;
        if (odd) {
            if (fwd) { hh++; if (hh == cH) { hh = 0; ww++; } }
            else { hh--; if (hh < 0) { hh = cH - 1; ww--; } }
        }
    }
}

// ---------------- combine 4 directions + out-LN + silu(z) multiply ----------------
__global__ void lnout_kernel(const float* __restrict__ ys, const float* __restrict__ xz,
                             const float* __restrict__ g, const float* __restrict__ b,
                             float* __restrict__ ymul) {
    int wid = threadIdx.x >> 6, lane = threadIdx.x & 63;
    int l = blockIdx.x * 4 + wid;
    if (l >= cL) return;
    int h_ = l / cW, w_ = l % cW;
    int lc = w_ * cH + h_;
    float v[3];
    float s = 0.f, sq = 0.f;
#pragma unroll
    for (int j = 0; j < 3; j++) {
        int d = lane + j * 64;
        float t = ys[(size_t)(0 * cL + l) * cDI + d] + ys[(size_t)(2 * cL + l) * cDI + d] +
                  ys[(size_t)(1 * cL + lc) * cDI + d] + ys[(size_t)(3 * cL + lc) * cDI + d];
        v[j] = t;
        s += t;
        sq += t * t;
    }
#pragma unroll
    for (int off = 32; off; off >>= 1) {
        s += __shfl_xor(s, off, 64);
        sq += __shfl_xor(sq, off, 64);
    }
    float m = s * (1.f / cDI);
    float var = sq * (1.f / cDI) - m * m;
    float rstd = rsqrtf(var + 1e-5f);
#pragma unroll
    for (int j = 0; j < 3; j++) {
        int d = lane + j * 64;
        float z = xz[(size_t)l * (2 * cDI) + cDI + d];
        ymul[(size_t)l * cDI + d] = ((v[j] - m) * rstd * g[d] + b[d]) * siluf(z);
    }
}

extern "C" void kernel_launch(void* const* d_in, const int* in_sizes, int n_in,
                              void* d_out, int out_size, void* d_ws, size_t ws_size,
                              hipStream_t stream) {
    const float* x         = (const float*)d_in[0];
    const float* norm_g    = (const float*)d_in[1];
    const float* norm_b    = (const float*)d_in[2];
    const float* in_proj_w = (const float*)d_in[3];
    const float* conv_w    = (const float*)d_in[4];
    const float* conv_b    = (const float*)d_in[5];
    const float* x_proj_w  = (const float*)d_in[6];
    const float* dt_projs_w= (const float*)d_in[7];
    const float* dt_projs_b= (const float*)d_in[8];
    const float* A_logs    = (const float*)d_in[9];
    const float* Ds        = (const float*)d_in[10];
    const float* out_norm_g= (const float*)d_in[11];
    const float* out_norm_b= (const float*)d_in[12];
    const float* out_proj_w= (const float*)d_in[13];
    const float* norm2_g   = (const float*)d_in[14];
    const float* norm2_b   = (const float*)d_in[15];
    const float* fc1_w     = (const float*)d_in[16];
    const float* fc1_b     = (const float*)d_in[17];
    const float* fc2_w     = (const float*)d_in[18];
    const float* fc2_b     = (const float*)d_in[19];

    float* ws = (float*)d_ws;
    float* ln_buf = ws;                    // L*96   = 301056
    float* xz     = ws + 301056;           // L*384  = 1204224
    float* xconv  = ws + 1505280;          // L*192  = 602112
    float* dtb_   = ws + 2107392;          // K*DI*L = 2408448
    float* Bs     = ws + 4515840;          // K*L*N  = 200704
    float* Cs     = ws + 4716544;          // 200704
    float* cP     = ws + 4917248;          // K*DI*NC*N = 196608
    float* cHh    = ws + 5113856;          // 196608
    float* hin    = ws + 5310464;          // 196608
    float* ys     = ws + 5507072;          // K*L*DI = 2408448
    float* ymul   = ws + 7915520;          // L*192  = 602112
    float* x1     = ws + 8517632;          // L*96   = 301056
    float* hm     = xz;                    // reuse xz (free after lnout) for MLP hidden
    float* out    = (float*)d_out;

    dim3 gblock(64, 4);

    // 1. LN1
    ln96_kernel<<<cL / 4, 256, 0, stream>>>(x, norm_g, norm_b, ln_buf, cL);
    // 2. in_proj GEMM: (L,96)@(96,384) -> xz
    gemm_kernel<0, false, false><<<dim3(3, cL / 4), gblock, 0, stream>>>(
        ln_buf, in_proj_w, nullptr, nullptr, xz, cL, 2 * cDI, cC);
    // 3. depthwise conv + silu
    conv_silu_kernel<<<(cL * cDI) / 256, 256, 0, stream>>>(xz, conv_w, conv_b, xconv);
    // 4. x_proj + dt_proj (physical positions)
    proj_kernel<<<dim3(cL / 16, cK), 256, 0, stream>>>(xconv, x_proj_w, dt_projs_w,
                                                       dt_projs_b, dtb_, Bs, Cs);
    // 5-7. chunked scan
    scan1_kernel<<<cK * (cDI / 16) * cNC, 256, 0, stream>>>(dtb_, Bs, xconv, A_logs, cP, cHh);
    scan2_kernel<<<(cK * cDI * cN + 255) / 256, 256, 0, stream>>>(cP, cHh, hin);
    scan3_kernel<<<cK * (cDI / 16) * cNC, 256, 0, stream>>>(dtb_, Bs, Cs, xconv, A_logs, Ds,
                                                            hin, ys);
    // 8. combine directions + out LN + silu(z)
    lnout_kernel<<<cL / 4, 256, 0, stream>>>(ys, xz, out_norm_g, out_norm_b, ymul);
    // 9. out_proj GEMM + residual(x) -> x1
    gemm_kernel<0, false, true><<<dim3(1, cL / 4), gblock, 0, stream>>>(
        ymul, out_proj_w, nullptr, x, x1, cL, cC, cDI);
    // 10. LN2
    ln96_kernel<<<cL / 4, 256, 0, stream>>>(x1, norm2_g, norm2_b, ln_buf, cL);
    // 11. fc1 + bias + gelu
    gemm_kernel<1, true, false><<<dim3(3, cL / 4), gblock, 0, stream>>>(
        ln_buf, fc1_w, fc1_b, nullptr, hm, cL, cMH, cC);
    // 12. fc2 + bias + residual(x1) -> out
    gemm_kernel<0, true, true><<<dim3(1, cL / 4), gblock, 0, stream>>>(
        hm, fc2_w, fc2_b, x1, out, cL, cC, cMH);
}

// Round 2
// 325.105 us; speedup vs baseline: 1.1145x; 1.1145x over previous
//
#include <hip/hip_runtime.h>
#include <math.h>

constexpr int cH = 56, cW = 56, cC = 96, cDI = 192, cN = 16, cDR = 6, cK = 4, cMH = 384;
constexpr int cL = cH * cW;          // 3136
constexpr int cNC = 49;              // number of scan chunks
constexpr int cCH = cL / cNC;        // 64 chunk length
constexpr float LOG2E = 1.44269504088896340736f;

__device__ __forceinline__ float fast_exp2(float x) { return __builtin_amdgcn_exp2f(x); }
__device__ __forceinline__ float siluf(float x) { return x / (1.f + expf(-x)); }
__device__ __forceinline__ float geluf(float x) {
    float x3 = x * x * x;
    return 0.5f * x * (1.f + tanhf(0.7978845608028654f * (x + 0.044715f * x3)));
}

// ---------------- LayerNorm over 96 cols, one wave per row ----------------
__global__ void ln96_kernel(const float* __restrict__ x, const float* __restrict__ g,
                            const float* __restrict__ b, float* __restrict__ out, int M) {
    int wid = threadIdx.x >> 6;
    int lane = threadIdx.x & 63;
    int row = blockIdx.x * 4 + wid;
    if (row >= M) return;
    const float* xr = x + row * cC;
    float v0 = xr[lane];
    float v1 = (lane < cC - 64) ? xr[lane + 64] : 0.f;
    float s = v0 + v1;
    float sq = v0 * v0 + v1 * v1;
#pragma unroll
    for (int off = 32; off; off >>= 1) {
        s += __shfl_xor(s, off, 64);
        sq += __shfl_xor(sq, off, 64);
    }
    float m = s * (1.f / cC);
    float var = sq * (1.f / cC) - m * m;
    float rstd = rsqrtf(var + 1e-5f);
    out[row * cC + lane] = (v0 - m) * rstd * g[lane] + b[lane];
    if (lane < cC - 64)
        out[row * cC + lane + 64] = (v1 - m) * rstd * g[lane + 64] + b[lane + 64];
}

// ---------------- generic fp32 GEMM: C = A(MxK) @ B(KxN) [+bias][gelu][+res] --------
// block (64,4): each thread does 1 row x 2 cols
template <int ACT, bool HASB, bool HASR>
__global__ void gemm_kernel(const float* __restrict__ A, const float* __restrict__ B,
                            const float* __restrict__ bias, const float* __restrict__ res,
                            float* __restrict__ C, int M, int Nn, int Kk) {
    int c0 = blockIdx.x * 128 + threadIdx.x * 2;
    int row = blockIdx.y * 4 + threadIdx.y;
    if (row >= M || c0 >= Nn) return;
    const float* Ar = A + row * Kk;
    float a0 = 0.f, a1 = 0.f;
#pragma unroll 4
    for (int k = 0; k < Kk; k++) {
        float av = Ar[k];
        const float2 bv = *reinterpret_cast<const float2*>(B + (size_t)k * Nn + c0);
        a0 = fmaf(av, bv.x, a0);
        a1 = fmaf(av, bv.y, a1);
    }
    if (HASB) { a0 += bias[c0]; a1 += bias[c0 + 1]; }
    if (ACT == 1) { a0 = geluf(a0); a1 = geluf(a1); }
    if (HASR) { a0 += res[row * Nn + c0]; a1 += res[row * Nn + c0 + 1]; }
    C[row * Nn + c0] = a0;
    C[row * Nn + c0 + 1] = a1;
}

// ---------------- depthwise 3x3 conv + bias + silu ----------------
__global__ void conv_silu_kernel(const float* __restrict__ xz, const float* __restrict__ cw,
                                 const float* __restrict__ cb, float* __restrict__ out) {
    int idx = blockIdx.x * 256 + threadIdx.x;
    if (idx >= cL * cDI) return;
    int d = idx % cDI;
    int l = idx / cDI;
    int h = l / cW, w = l % cW;
    float s = cb[d];
#pragma unroll
    for (int dh = 0; dh < 3; dh++) {
        int hh = h + dh - 1;
        if (hh < 0 || hh >= cH) continue;
#pragma unroll
        for (int dw = 0; dw < 3; dw++) {
            int w2 = w + dw - 1;
            if (w2 < 0 || w2 >= cW) continue;
            s = fmaf(xz[(size_t)(hh * cW + w2) * (2 * cDI) + d], cw[(dh * 3 + dw) * cDI + d], s);
        }
    }
    out[idx] = siluf(s);
}

// ---------------- x_proj + dt_proj per (k, 16 physical positions) ----------------
__global__ void proj_kernel(const float* __restrict__ xconv, const float* __restrict__ xpw,
                            const float* __restrict__ dtw, const float* __restrict__ dtb,
                            float* __restrict__ dtout, float* __restrict__ Bsout,
                            float* __restrict__ Csout) {
    __shared__ float XS[16 * 193];
    __shared__ float DTS[6 * 16];
    int k = blockIdx.y;
    int p0 = blockIdx.x * 16;
    int tid = threadIdx.x;
    for (int idx = tid; idx < 16 * cDI; idx += 256) {
        int p = idx / cDI, d = idx % cDI;
        int pp = p0 + p;
        int rrow;
        if (k & 1) { int h = pp % cH, w = pp / cH; rrow = h * cW + w; }
        else rrow = pp;
        XS[p * 193 + d] = xconv[(size_t)rrow * cDI + d];
    }
    __syncthreads();
    for (int o = tid; o < 38 * 16; o += 256) {
        int c = o >> 4, p = o & 15;
        const float* wr = xpw + (size_t)(k * 38 + c) * cDI;
        const float* xr = XS + p * 193;
        float s = 0.f;
#pragma unroll 4
        for (int d = 0; d < cDI; d++) s = fmaf(wr[d], xr[d], s);
        if (c < 6) DTS[c * 16 + p] = s;
        else if (c < 22) Bsout[(size_t)(k * cL + p0 + p) * cN + (c - 6)] = s;
        else Csout[(size_t)(k * cL + p0 + p) * cN + (c - 22)] = s;
    }
    __syncthreads();
    for (int o = tid; o < cDI * 16; o += 256) {
        int d = o >> 4, p = o & 15;
        float s = dtb[k * cDI + d];
        const float* wr = dtw + (size_t)(k * cDI + d) * cDR;
#pragma unroll
        for (int r = 0; r < cDR; r++) s = fmaf(wr[r], DTS[r * 16 + p], s);
        float sp = (s > 20.f) ? s : log1pf(expf(s));
        dtout[(size_t)(k * cDI + d) * cL + p0 + p] = sp;
    }
}

// ---------------- scan pass 1: per-chunk local scan (h starts at 0) ----------------
// block 256 = 16 groups(d) x 16 lanes(n); block -> (k, d0..d0+15, chunk)
__global__ void scan1_kernel(const float* __restrict__ dtbuf, const float* __restrict__ Bs,
                             const float* __restrict__ xconv, const float* __restrict__ Alogs,
                             float* __restrict__ carryP, float* __restrict__ carryH) {
    int bx = blockIdx.x;
    int c = bx % cNC;
    int t2 = bx / cNC;
    int d0 = (t2 % (cDI / 16)) * 16;
    int k = t2 / (cDI / 16);
    int g = threadIdx.x >> 4;
    int n = threadIdx.x & 15;
    int d = d0 + g;
    int kd = k * cDI + d;
    float An2 = -expf(Alogs[kd * cN + n]) * LOG2E;
    bool fwd = (k < 2);
    bool odd = (k & 1);
    int s0 = c * cCH;
    int hh = 0, ww = 0;
    if (odd) {
        int lc0 = fwd ? s0 : (cL - 1 - s0);
        hh = lc0 % cH;
        ww = lc0 / cH;
    }
    const float* dtp = dtbuf + (size_t)kd * cL;
    const float* bsp = Bs + (size_t)k * cL * cN + n;
    float h = 0.f, S = 0.f;
    for (int i = 0; i < cCH; i++) {
        int l = fwd ? (s0 + i) : (cL - 1 - s0 - i);
        float dt = dtp[l];
        int xr = odd ? (hh * cW + ww) : l;
        float xv = xconv[(size_t)xr * cDI + d];
        float bv = bsp[(size_t)l * cN];
        float a = fast_exp2(An2 * dt);
        h = fmaf(a, h, dt * bv * xv);
        S += dt;
        if (odd) {
            if (fwd) { hh++; if (hh == cH) { hh = 0; ww++; } }
            else { hh--; if (hh < 0) { hh = cH - 1; ww--; } }
        }
    }
    float P = fast_exp2(An2 * S);
    int idxc = (kd * cNC + c) * cN + n;
    carryH[idxc] = h;
    carryP[idxc] = P;
}

// ---------------- scan pass 2: sequential carry combine across chunks ----------------
__global__ void scan2_kernel(const float* __restrict__ carryP, const float* __restrict__ carryH,
                             float* __restrict__ hin) {
    int gid = blockIdx.x * 256 + threadIdx.x;
    if (gid >= cK * cDI * cN) return;
    int kd = gid / cN, n = gid % cN;
    float h = 0.f;
    for (int c = 0; c < cNC; c++) {
        int idxc = (kd * cNC + c) * cN + n;
        hin[idxc] = h;
        h = fmaf(carryP[idxc], h, carryH[idxc]);
    }
}

// ---------------- scan pass 3: local scan with carry seed + C-contraction ----------------
// writes ys [K][L][DI] at PHYSICAL position
__global__ void scan3_kernel(const float* __restrict__ dtbuf, const float* __restrict__ Bs,
                             const float* __restrict__ Cs, const float* __restrict__ xconv,
                             const float* __restrict__ Alogs, const float* __restrict__ Ds,
                             const float* __restrict__ hin, float* __restrict__ ys) {
    int bx = blockIdx.x;
    int c = bx % cNC;
    int t2 = bx / cNC;
    int d0 = (t2 % (cDI / 16)) * 16;
    int k = t2 / (cDI / 16);
    int g = threadIdx.x >> 4;
    int n = threadIdx.x & 15;
    int d = d0 + g;
    int kd = k * cDI + d;
    float An2 = -expf(Alogs[kd * cN + n]) * LOG2E;
    float Dv = Ds[kd];
    bool fwd = (k < 2);
    bool odd = (k & 1);
    int s0 = c * cCH;
    int hh = 0, ww = 0;
    if (odd) {
        int lc0 = fwd ? s0 : (cL - 1 - s0);
        hh = lc0 % cH;
        ww = lc0 / cH;
    }
    const float* dtp = dtbuf + (size_t)kd * cL;
    const float* bsp = Bs + (size_t)k * cL * cN + n;
    const float* csp = Cs + (size_t)k * cL * cN + n;
    float h = hin[(kd * cNC + c) * cN + n];
    for (int i = 0; i < cCH; i++) {
        int l = fwd ? (s0 + i) : (cL - 1 - s0 - i);
        float dt = dtp[l];
        int xr = odd ? (hh * cW + ww) : l;
        float xv = xconv[(size_t)xr * cDI + d];
        float bv = bsp[(size_t)l * cN];
        float a = fast_exp2(An2 * dt);
        h = fmaf(a, h, dt * bv * xv);
        float t = h * csp[(size_t)l * cN];
        t += __shfl_xor(t, 8, 16);
        t += __shfl_xor(t, 4, 16);
        t += __shfl_xor(t, 2, 16);
        t += __shfl_xor(t, 1, 16);
        if (n == 0) ys[(size_t)(k * cL + l) * cDI + d] = t + Dv * xv;
        if (odd) {
            if (fwd) { hh++; if (hh == cH) { hh = 0; ww++; } }
            else { hh--; if (hh < 0) { hh = cH - 1; ww--; } }
        }
    }
}

// ---------------- combine 4 directions + out-LN + silu(z) multiply ----------------
__global__ void lnout_kernel(const float* __restrict__ ys, const float* __restrict__ xz,
                             const float* __restrict__ g, const float* __restrict__ b,
                             float* __restrict__ ymul) {
    int wid = threadIdx.x >> 6, lane = threadIdx.x & 63;
    int l = blockIdx.x * 4 + wid;
    if (l >= cL) return;
    int h_ = l / cW, w_ = l % cW;
    int lc = w_ * cH + h_;
    float v[3];
    float s = 0.f, sq = 0.f;
#pragma unroll
    for (int j = 0; j < 3; j++) {
        int d = lane + j * 64;
        float t = ys[(size_t)(0 * cL + l) * cDI + d] + ys[(size_t)(2 * cL + l) * cDI + d] +
                  ys[(size_t)(1 * cL + lc) * cDI + d] + ys[(size_t)(3 * cL + lc) * cDI + d];
        v[j] = t;
        s += t;
        sq += t * t;
    }
#pragma unroll
    for (int off = 32; off; off >>= 1) {
        s += __shfl_xor(s, off, 64);
        sq += __shfl_xor(sq, off, 64);
    }
    float m = s * (1.f / cDI);
    float var = sq * (1.f / cDI) - m * m;
    float rstd = rsqrtf(var + 1e-5f);
#pragma unroll
    for (int j = 0; j < 3; j++) {
        int d = lane + j * 64;
        float z = xz[(size_t)l * (2 * cDI) + cDI + d];
        ymul[(size_t)l * cDI + d] = ((v[j] - m) * rstd * g[d] + b[d]) * siluf(z);
    }
}

extern "C" void kernel_launch(void* const* d_in, const int* in_sizes, int n_in,
                              void* d_out, int out_size, void* d_ws, size_t ws_size,
                              hipStream_t stream) {
    const float* x         = (const float*)d_in[0];
    const float* norm_g    = (const float*)d_in[1];
    const float* norm_b    = (const float*)d_in[2];
    const float* in_proj_w = (const float*)d_in[3];
    const float* conv_w    = (const float*)d_in[4];
    const float* conv_b    = (const float*)d_in[5];
    const float* x_proj_w  = (const float*)d_in[6];
    const float* dt_projs_w= (const float*)d_in[7];
    const float* dt_projs_b= (const float*)d_in[8];
    const float* A_logs    = (const float*)d_in[9];
    const float* Ds        = (const float*)d_in[10];
    const float* out_norm_g= (const float*)d_in[11];
    const float* out_norm_b= (const float*)d_in[12];
    const float* out_proj_w= (const float*)d_in[13];
    const float* norm2_g   = (const float*)d_in[14];
    const float* norm2_b   = (const float*)d_in[15];
    const float* fc1_w     = (const float*)d_in[16];
    const float* fc1_b     = (const float*)d_in[17];
    const float* fc2_w     = (const float*)d_in[18];
    const float* fc2_b     = (const float*)d_in[19];

    float* ws = (float*)d_ws;
    float* ln_buf = ws;                    // 301056
    float* xz     = ws + 301056;           // 1204224
    float* xconv  = ws + 1505280;          // 602112
    float* dtb_   = ws + 2107392;          // 2408448
    float* Bs     = ws + 4515840;          // 200704
    float* Cs     = ws + 4716544;          // 200704
    float* hin    = ws + 4917248;          // K*DI*NC*N = 602112
    float* ys     = ws + 5519360;          // 2408448 (cP/cHh alias here pre-scan3)
    float* cP     = ys;                    // 602112 (dead once scan2 done)
    float* cHh    = ys + 602112;           // 602112 (dead once scan2 done)
    float* ymul   = ws + 7927808;          // 602112
    float* x1     = ws + 8529920;          // 301056
    float* hm     = xz;                    // reuse xz for MLP hidden
    float* out    = (float*)d_out;

    dim3 gblock(64, 4);

    // 1. LN1
    ln96_kernel<<<cL / 4, 256, 0, stream>>>(x, norm_g, norm_b, ln_buf, cL);
    // 2. in_proj GEMM
    gemm_kernel<0, false, false><<<dim3(3, cL / 4), gblock, 0, stream>>>(
        ln_buf, in_proj_w, nullptr, nullptr, xz, cL, 2 * cDI, cC);
    // 3. depthwise conv + silu
    conv_silu_kernel<<<(cL * cDI) / 256, 256, 0, stream>>>(xz, conv_w, conv_b, xconv);
    // 4. x_proj + dt_proj
    proj_kernel<<<dim3(cL / 16, cK), 256, 0, stream>>>(xconv, x_proj_w, dt_projs_w,
                                                       dt_projs_b, dtb_, Bs, Cs);
    // 5-7. chunked scan
    scan1_kernel<<<cK * (cDI / 16) * cNC, 256, 0, stream>>>(dtb_, Bs, xconv, A_logs, cP, cHh);
    scan2_kernel<<<(cK * cDI * cN + 255) / 256, 256, 0, stream>>>(cP, cHh, hin);
    scan3_kernel<<<cK * (cDI / 16) * cNC, 256, 0, stream>>>(dtb_, Bs, Cs, xconv, A_logs, Ds,
                                                            hin, ys);
    // 8. combine + out LN + silu(z)
    lnout_kernel<<<cL / 4, 256, 0, stream>>>(ys, xz, out_norm_g, out_norm_b, ymul);
    // 9. out_proj + residual
    gemm_kernel<0, false, true><<<dim3(1, cL / 4), gblock, 0, stream>>>(
        ymul, out_proj_w, nullptr, x, x1, cL, cC, cDI);
    // 10. LN2
    ln96_kernel<<<cL / 4, 256, 0, stream>>>(x1, norm2_g, norm2_b, ln_buf, cL);
    // 11. fc1 + bias + gelu
    gemm_kernel<1, true, false><<<dim3(3, cL / 4), gblock, 0, stream>>>(
        ln_buf, fc1_w, fc1_b, nullptr, hm, cL, cMH, cC);
    // 12. fc2 + bias + residual
    gemm_kernel<0, true, true><<<dim3(1, cL / 4), gblock, 0, stream>>>(
        hm, fc2_w, fc2_b, x1, out, cL, cC, cMH);
}

// Round 3
// 278.373 us; speedup vs baseline: 1.3016x; 1.1679x over previous
//
#include <hip/hip_runtime.h>
#include <math.h>

constexpr int cH = 56, cW = 56, cC = 96, cDI = 192, cN = 16, cDR = 6, cK = 4, cMH = 384;
constexpr int cL = cH * cW;          // 3136
constexpr int cNC = 49;              // scan chunks
constexpr int cCH = 64;              // chunk length
constexpr float LOG2E = 1.44269504088896340736f;

__device__ __forceinline__ float fast_exp2(float x) { return __builtin_amdgcn_exp2f(x); }
__device__ __forceinline__ float siluf(float x) { return x / (1.f + expf(-x)); }
__device__ __forceinline__ float geluf(float x) {
    float x3 = x * x * x;
    return 0.5f * x * (1.f + tanhf(0.7978845608028654f * (x + 0.044715f * x3)));
}

// sum over 16-lane group via DPP butterfly (pure VALU, no DS pipe)
__device__ __forceinline__ float dpp_red16(float v) {
    union { float f; int i; } u, r;
    u.f = v; r.i = __builtin_amdgcn_update_dpp(0, u.i, 0xB1, 0xF, 0xF, true);  v += r.f; // quad xor1
    u.f = v; r.i = __builtin_amdgcn_update_dpp(0, u.i, 0x4E, 0xF, 0xF, true);  v += r.f; // quad xor2
    u.f = v; r.i = __builtin_amdgcn_update_dpp(0, u.i, 0x141, 0xF, 0xF, true); v += r.f; // half_mirror
    u.f = v; r.i = __builtin_amdgcn_update_dpp(0, u.i, 0x140, 0xF, 0xF, true); v += r.f; // mirror
    return v;
}

// ---------------- LayerNorm over 96 cols, one wave per row ----------------
__global__ void ln96_kernel(const float* __restrict__ x, const float* __restrict__ g,
                            const float* __restrict__ b, float* __restrict__ out, int M) {
    int wid = threadIdx.x >> 6;
    int lane = threadIdx.x & 63;
    int row = blockIdx.x * 4 + wid;
    if (row >= M) return;
    const float* xr = x + row * cC;
    float v0 = xr[lane];
    float v1 = (lane < cC - 64) ? xr[lane + 64] : 0.f;
    float s = v0 + v1;
    float sq = v0 * v0 + v1 * v1;
#pragma unroll
    for (int off = 32; off; off >>= 1) {
        s += __shfl_xor(s, off, 64);
        sq += __shfl_xor(sq, off, 64);
    }
    float m = s * (1.f / cC);
    float var = sq * (1.f / cC) - m * m;
    float rstd = rsqrtf(var + 1e-5f);
    out[row * cC + lane] = (v0 - m) * rstd * g[lane] + b[lane];
    if (lane < cC - 64)
        out[row * cC + lane + 64] = (v1 - m) * rstd * g[lane + 64] + b[lane + 64];
}

// ---------------- generic fp32 GEMM ----------------
template <int ACT, bool HASB, bool HASR>
__global__ void gemm_kernel(const float* __restrict__ A, const float* __restrict__ B,
                            const float* __restrict__ bias, const float* __restrict__ res,
                            float* __restrict__ C, int M, int Nn, int Kk) {
    int c0 = blockIdx.x * 128 + threadIdx.x * 2;
    int row = blockIdx.y * 4 + threadIdx.y;
    if (row >= M || c0 >= Nn) return;
    const float* Ar = A + row * Kk;
    float a0 = 0.f, a1 = 0.f;
#pragma unroll 4
    for (int k = 0; k < Kk; k++) {
        float av = Ar[k];
        const float2 bv = *reinterpret_cast<const float2*>(B + (size_t)k * Nn + c0);
        a0 = fmaf(av, bv.x, a0);
        a1 = fmaf(av, bv.y, a1);
    }
    if (HASB) { a0 += bias[c0]; a1 += bias[c0 + 1]; }
    if (ACT == 1) { a0 = geluf(a0); a1 = geluf(a1); }
    if (HASR) { a0 += res[row * Nn + c0]; a1 += res[row * Nn + c0 + 1]; }
    C[row * Nn + c0] = a0;
    C[row * Nn + c0 + 1] = a1;
}

// ---------------- depthwise 3x3 conv + bias + silu ----------------
__global__ void conv_silu_kernel(const float* __restrict__ xz, const float* __restrict__ cw,
                                 const float* __restrict__ cb, float* __restrict__ out) {
    int idx = blockIdx.x * 256 + threadIdx.x;
    if (idx >= cL * cDI) return;
    int d = idx % cDI;
    int l = idx / cDI;
    int h = l / cW, w = l % cW;
    float s = cb[d];
#pragma unroll
    for (int dh = 0; dh < 3; dh++) {
        int hh = h + dh - 1;
        if (hh < 0 || hh >= cH) continue;
#pragma unroll
        for (int dw = 0; dw < 3; dw++) {
            int w2 = w + dw - 1;
            if (w2 < 0 || w2 >= cW) continue;
            s = fmaf(xz[(size_t)(hh * cW + w2) * (2 * cDI) + d], cw[(dh * 3 + dw) * cDI + d], s);
        }
    }
    out[idx] = siluf(s);
}

// ---------------- x_proj + dt_proj; outputs stored in SCAN order j ----------------
__global__ void proj_kernel(const float* __restrict__ xconv, const float* __restrict__ xpw,
                            const float* __restrict__ dtw, const float* __restrict__ dtb,
                            float* __restrict__ dtout, float* __restrict__ Bsout,
                            float* __restrict__ Csout) {
    __shared__ float XS[16 * 193];
    __shared__ float DTS[6 * 16];
    int k = blockIdx.y;
    int p0 = blockIdx.x * 16;
    int tid = threadIdx.x;
    for (int idx = tid; idx < 16 * cDI; idx += 256) {
        int p = idx / cDI, d = idx % cDI;
        int j = p0 + p;
        int jj = (k >= 2) ? (cL - 1 - j) : j;
        int rrow = (k & 1) ? ((jj % cH) * cW + (jj / cH)) : jj;
        XS[p * 193 + d] = xconv[(size_t)rrow * cDI + d];
    }
    __syncthreads();
    for (int o = tid; o < 38 * 16; o += 256) {
        int c = o >> 4, p = o & 15;
        const float* wr = xpw + (size_t)(k * 38 + c) * cDI;
        const float* xr = XS + p * 193;
        float s = 0.f;
#pragma unroll 4
        for (int d = 0; d < cDI; d++) s = fmaf(wr[d], xr[d], s);
        if (c < 6) DTS[c * 16 + p] = s;
        else if (c < 22) Bsout[(size_t)(k * cL + p0 + p) * cN + (c - 6)] = s;
        else Csout[(size_t)(k * cL + p0 + p) * cN + (c - 22)] = s;
    }
    __syncthreads();
    for (int o = tid; o < cDI * 16; o += 256) {
        int d = o >> 4, p = o & 15;
        float s = dtb[k * cDI + d];
        const float* wr = dtw + (size_t)(k * cDI + d) * cDR;
#pragma unroll
        for (int r = 0; r < cDR; r++) s = fmaf(wr[r], DTS[r * 16 + p], s);
        float sp = (s > 20.f) ? s : log1pf(expf(s));
        dtout[(size_t)(k * cDI + d) * cL + p0 + p] = sp;
    }
}

// physical-row walker init/step for direction k at scan index j
__device__ __forceinline__ void walker_init(int k, int j0, int& r, int& dr) {
    if (k == 0) { r = j0; dr = 1; }
    else if (k == 1) { r = (j0 % cH) * cW + (j0 / cH); dr = cW; }
    else if (k == 2) { r = cL - 1 - j0; dr = -1; }
    else { int jp = cL - 1 - j0; r = (jp % cH) * cW + (jp / cH); dr = -cW; }
}
__device__ __forceinline__ void walker_step(int& r, int dr) {
    r += dr;
    if (r >= cL) r -= cL - 1;
    else if (r < 0) r += cL - 1;
}

// ---------------- scan pass 1: per-chunk local scan ----------------
// block 256 = 16 groups(d) x 16 lanes(n); block -> (k, d0..d0+15, chunk)
__global__ void scan1_kernel(const float* __restrict__ dtbuf, const float* __restrict__ Bs,
                             const float* __restrict__ xconv, const float* __restrict__ Alogs,
                             float* __restrict__ carryP, float* __restrict__ carryH) {
    int bx = blockIdx.x;
    int c = bx % cNC;
    int t2 = bx / cNC;
    int d0 = (t2 % (cDI / 16)) * 16;
    int k = t2 / (cDI / 16);
    int g = threadIdx.x >> 4;
    int n = threadIdx.x & 15;
    int d = d0 + g;
    int kd = k * cDI + d;
    float An2 = -expf(Alogs[kd * cN + n]) * LOG2E;
    int j0 = c * cCH;
    int r, dr;
    walker_init(k, j0, r, dr);
    const float* dtp = dtbuf + (size_t)kd * cL;
    const float* bsp = Bs + (size_t)k * cL * cN + n;
    float h = 0.f, S = 0.f;
    for (int i = 0; i < cCH; i += 4) {
        int j = j0 + i;
        const float4 dt4 = *reinterpret_cast<const float4*>(dtp + j);
        float xv0 = xconv[r * cDI + d]; walker_step(r, dr);
        float xv1 = xconv[r * cDI + d]; walker_step(r, dr);
        float xv2 = xconv[r * cDI + d]; walker_step(r, dr);
        float xv3 = xconv[r * cDI + d]; walker_step(r, dr);
        float bv0 = bsp[(size_t)(j + 0) * cN];
        float bv1 = bsp[(size_t)(j + 1) * cN];
        float bv2 = bsp[(size_t)(j + 2) * cN];
        float bv3 = bsp[(size_t)(j + 3) * cN];
        float a0 = fast_exp2(An2 * dt4.x);
        float a1 = fast_exp2(An2 * dt4.y);
        float a2 = fast_exp2(An2 * dt4.z);
        float a3 = fast_exp2(An2 * dt4.w);
        h = fmaf(a0, h, dt4.x * bv0 * xv0);
        h = fmaf(a1, h, dt4.y * bv1 * xv1);
        h = fmaf(a2, h, dt4.z * bv2 * xv2);
        h = fmaf(a3, h, dt4.w * bv3 * xv3);
        S += dt4.x + dt4.y + dt4.z + dt4.w;
    }
    float P = fast_exp2(An2 * S);
    int idxc = (kd * cNC + c) * cN + n;
    carryH[idxc] = h;
    carryP[idxc] = P;
}

// ---------------- scan pass 2: sequential carry combine ----------------
__global__ void scan2_kernel(const float* __restrict__ carryP, const float* __restrict__ carryH,
                             float* __restrict__ hin) {
    int gid = blockIdx.x * 256 + threadIdx.x;
    if (gid >= cK * cDI * cN) return;
    int kd = gid / cN, n = gid % cN;
    float h = 0.f;
    for (int c = 0; c < cNC; c++) {
        int idxc = (kd * cNC + c) * cN + n;
        hin[idxc] = h;
        h = fmaf(carryP[idxc], h, carryH[idxc]);
    }
}

// ---------------- scan pass 3: seeded local scan + C-contraction ----------------
// writes ysS [K][j][DI] in SCAN order
__global__ void scan3_kernel(const float* __restrict__ dtbuf, const float* __restrict__ Bs,
                             const float* __restrict__ Cs, const float* __restrict__ xconv,
                             const float* __restrict__ Alogs, const float* __restrict__ Ds,
                             const float* __restrict__ hin, float* __restrict__ ysS) {
    int bx = blockIdx.x;
    int c = bx % cNC;
    int t2 = bx / cNC;
    int d0 = (t2 % (cDI / 16)) * 16;
    int k = t2 / (cDI / 16);
    int g = threadIdx.x >> 4;
    int n = threadIdx.x & 15;
    int d = d0 + g;
    int kd = k * cDI + d;
    float An2 = -expf(Alogs[kd * cN + n]) * LOG2E;
    float Dv = Ds[kd];
    int j0 = c * cCH;
    int r, dr;
    walker_init(k, j0, r, dr);
    const float* dtp = dtbuf + (size_t)kd * cL;
    const float* bsp = Bs + (size_t)k * cL * cN + n;
    const float* csp = Cs + (size_t)k * cL * cN + n;
    float h = hin[(kd * cNC + c) * cN + n];
    for (int i = 0; i < cCH; i += 4) {
        int j = j0 + i;
        const float4 dt4 = *reinterpret_cast<const float4*>(dtp + j);
        float xv0 = xconv[r * cDI + d]; walker_step(r, dr);
        float xv1 = xconv[r * cDI + d]; walker_step(r, dr);
        float xv2 = xconv[r * cDI + d]; walker_step(r, dr);
        float xv3 = xconv[r * cDI + d]; walker_step(r, dr);
        float bv0 = bsp[(size_t)(j + 0) * cN];
        float bv1 = bsp[(size_t)(j + 1) * cN];
        float bv2 = bsp[(size_t)(j + 2) * cN];
        float bv3 = bsp[(size_t)(j + 3) * cN];
        float cv0 = csp[(size_t)(j + 0) * cN];
        float cv1 = csp[(size_t)(j + 1) * cN];
        float cv2 = csp[(size_t)(j + 2) * cN];
        float cv3 = csp[(size_t)(j + 3) * cN];
        float a0 = fast_exp2(An2 * dt4.x);
        float a1 = fast_exp2(An2 * dt4.y);
        float a2 = fast_exp2(An2 * dt4.z);
        float a3 = fast_exp2(An2 * dt4.w);
        h = fmaf(a0, h, dt4.x * bv0 * xv0);
        float t0 = dpp_red16(h * cv0);
        h = fmaf(a1, h, dt4.y * bv1 * xv1);
        float t1 = dpp_red16(h * cv1);
        h = fmaf(a2, h, dt4.z * bv2 * xv2);
        float t2v = dpp_red16(h * cv2);
        h = fmaf(a3, h, dt4.w * bv3 * xv3);
        float t3 = dpp_red16(h * cv3);
        if (n == 0) {
            ysS[(size_t)(k * cL + j + 0) * cDI + d] = t0 + Dv * xv0;
            ysS[(size_t)(k * cL + j + 1) * cDI + d] = t1 + Dv * xv1;
            ysS[(size_t)(k * cL + j + 2) * cDI + d] = t2v + Dv * xv2;
            ysS[(size_t)(k * cL + j + 3) * cDI + d] = t3 + Dv * xv3;
        }
    }
}

// ---------------- combine 4 directions + out-LN + silu(z) ----------------
__global__ void lnout_kernel(const float* __restrict__ ysS, const float* __restrict__ xz,
                             const float* __restrict__ g, const float* __restrict__ b,
                             float* __restrict__ ymul) {
    int wid = threadIdx.x >> 6, lane = threadIdx.x & 63;
    int l = blockIdx.x * 4 + wid;
    if (l >= cL) return;
    int h_ = l / cW, w_ = l % cW;
    int lc = w_ * cH + h_;
    float v[3];
    float s = 0.f, sq = 0.f;
#pragma unroll
    for (int j = 0; j < 3; j++) {
        int d = lane + j * 64;
        float t = ysS[(size_t)(0 * cL + l) * cDI + d] +
                  ysS[(size_t)(1 * cL + lc) * cDI + d] +
                  ysS[(size_t)(2 * cL + (cL - 1 - l)) * cDI + d] +
                  ysS[(size_t)(3 * cL + (cL - 1 - lc)) * cDI + d];
        v[j] = t;
        s += t;
        sq += t * t;
    }
#pragma unroll
    for (int off = 32; off; off >>= 1) {
        s += __shfl_xor(s, off, 64);
        sq += __shfl_xor(sq, off, 64);
    }
    float m = s * (1.f / cDI);
    float var = sq * (1.f / cDI) - m * m;
    float rstd = rsqrtf(var + 1e-5f);
#pragma unroll
    for (int j = 0; j < 3; j++) {
        int d = lane + j * 64;
        float z = xz[(size_t)l * (2 * cDI) + cDI + d];
        ymul[(size_t)l * cDI + d] = ((v[j] - m) * rstd * g[d] + b[d]) * siluf(z);
    }
}

extern "C" void kernel_launch(void* const* d_in, const int* in_sizes, int n_in,
                              void* d_out, int out_size, void* d_ws, size_t ws_size,
                              hipStream_t stream) {
    const float* x         = (const float*)d_in[0];
    const float* norm_g    = (const float*)d_in[1];
    const float* norm_b    = (const float*)d_in[2];
    const float* in_proj_w = (const float*)d_in[3];
    const float* conv_w    = (const float*)d_in[4];
    const float* conv_b    = (const float*)d_in[5];
    const float* x_proj_w  = (const float*)d_in[6];
    const float* dt_projs_w= (const float*)d_in[7];
    const float* dt_projs_b= (const float*)d_in[8];
    const float* A_logs    = (const float*)d_in[9];
    const float* Ds        = (const float*)d_in[10];
    const float* out_norm_g= (const float*)d_in[11];
    const float* out_norm_b= (const float*)d_in[12];
    const float* out_proj_w= (const float*)d_in[13];
    const float* norm2_g   = (const float*)d_in[14];
    const float* norm2_b   = (const float*)d_in[15];
    const float* fc1_w     = (const float*)d_in[16];
    const float* fc1_b     = (const float*)d_in[17];
    const float* fc2_w     = (const float*)d_in[18];
    const float* fc2_b     = (const float*)d_in[19];

    float* ws = (float*)d_ws;
    float* ln_buf = ws;                    // 301056
    float* xz     = ws + 301056;           // 1204224
    float* xconv  = ws + 1505280;          // 602112 (ymul aliases after scan3)
    float* dtb_   = ws + 2107392;          // 2408448  [k][d][j] scan order
    float* Bs     = ws + 4515840;          // 200704   [k][j][n] scan order
    float* Cs     = ws + 4716544;          // 200704   [k][j][n] scan order
    float* hin    = ws + 4917248;          // 602112
    float* ysS    = ws + 5519360;          // 2408448  [k][j][d] scan order
    float* cP     = ysS;                   // 602112 (dead before scan3 writes)
    float* cHh    = ysS + 602112;          // 602112
    float* ymul   = xconv;                 // reuse xconv (dead after scan3)
    float* x1     = ws + 7927808;          // 301056
    float* hm     = xz;                    // reuse xz for MLP hidden
    float* out    = (float*)d_out;

    dim3 gblock(64, 4);

    // 1. LN1
    ln96_kernel<<<cL / 4, 256, 0, stream>>>(x, norm_g, norm_b, ln_buf, cL);
    // 2. in_proj GEMM
    gemm_kernel<0, false, false><<<dim3(3, cL / 4), gblock, 0, stream>>>(
        ln_buf, in_proj_w, nullptr, nullptr, xz, cL, 2 * cDI, cC);
    // 3. depthwise conv + silu
    conv_silu_kernel<<<(cL * cDI) / 256, 256, 0, stream>>>(xz, conv_w, conv_b, xconv);
    // 4. x_proj + dt_proj (scan-order outputs)
    proj_kernel<<<dim3(cL / 16, cK), 256, 0, stream>>>(xconv, x_proj_w, dt_projs_w,
                                                       dt_projs_b, dtb_, Bs, Cs);
    // 5-7. chunked scan
    scan1_kernel<<<cK * (cDI / 16) * cNC, 256, 0, stream>>>(dtb_, Bs, xconv, A_logs, cP, cHh);
    scan2_kernel<<<(cK * cDI * cN + 255) / 256, 256, 0, stream>>>(cP, cHh, hin);
    scan3_kernel<<<cK * (cDI / 16) * cNC, 256, 0, stream>>>(dtb_, Bs, Cs, xconv, A_logs, Ds,
                                                            hin, ysS);
    // 8. combine + out LN + silu(z)
    lnout_kernel<<<cL / 4, 256, 0, stream>>>(ysS, xz, out_norm_g, out_norm_b, ymul);
    // 9. out_proj + residual
    gemm_kernel<0, false, true><<<dim3(1, cL / 4), gblock, 0, stream>>>(
        ymul, out_proj_w, nullptr, x, x1, cL, cC, cDI);
    // 10. LN2
    ln96_kernel<<<cL / 4, 256, 0, stream>>>(x1, norm2_g, norm2_b, ln_buf, cL);
    // 11. fc1 + bias + gelu
    gemm_kernel<1, true, false><<<dim3(3, cL / 4), gblock, 0, stream>>>(
        ln_buf, fc1_w, fc1_b, nullptr, hm, cL, cMH, cC);
    // 12. fc2 + bias + residual
    gemm_kernel<0, true, true><<<dim3(1, cL / 4), gblock, 0, stream>>>(
        hm, fc2_w, fc2_b, x1, out, cL, cC, cMH);
}

// Round 4
// 162.370 us; speedup vs baseline: 2.2315x; 1.7144x over previous
//
#include <hip/hip_runtime.h>
#include <math.h>

constexpr int cH = 56, cW = 56, cC = 96, cDI = 192, cN = 16, cDR = 6, cK = 4, cMH = 384;
constexpr int cL = cH * cW;          // 3136
constexpr int cNC = 49;              // scan chunks
constexpr int cCH = 64;              // chunk length
constexpr float LOG2E = 1.44269504088896340736f;

__device__ __forceinline__ float fast_exp2(float x) { return __builtin_amdgcn_exp2f(x); }
__device__ __forceinline__ float siluf(float x) { return x / (1.f + expf(-x)); }
__device__ __forceinline__ float geluf(float x) {
    float x3 = x * x * x;
    return 0.5f * x * (1.f + tanhf(0.7978845608028654f * (x + 0.044715f * x3)));
}

// sum over 16-lane group via DPP butterfly (pure VALU, no DS pipe)
__device__ __forceinline__ float dpp_red16(float v) {
    union { float f; int i; } u, r;
    u.f = v; r.i = __builtin_amdgcn_update_dpp(0, u.i, 0xB1, 0xF, 0xF, true);  v += r.f;
    u.f = v; r.i = __builtin_amdgcn_update_dpp(0, u.i, 0x4E, 0xF, 0xF, true);  v += r.f;
    u.f = v; r.i = __builtin_amdgcn_update_dpp(0, u.i, 0x141, 0xF, 0xF, true); v += r.f;
    u.f = v; r.i = __builtin_amdgcn_update_dpp(0, u.i, 0x140, 0xF, 0xF, true); v += r.f;
    return v;
}

// ---------------- LayerNorm over 96 cols, one wave per row ----------------
__global__ void ln96_kernel(const float* __restrict__ x, const float* __restrict__ g,
                            const float* __restrict__ b, float* __restrict__ out, int M) {
    int wid = threadIdx.x >> 6;
    int lane = threadIdx.x & 63;
    int row = blockIdx.x * 4 + wid;
    if (row >= M) return;
    const float* xr = x + row * cC;
    float v0 = xr[lane];
    float v1 = (lane < cC - 64) ? xr[lane + 64] : 0.f;
    float s = v0 + v1;
    float sq = v0 * v0 + v1 * v1;
#pragma unroll
    for (int off = 32; off; off >>= 1) {
        s += __shfl_xor(s, off, 64);
        sq += __shfl_xor(sq, off, 64);
    }
    float m = s * (1.f / cC);
    float var = sq * (1.f / cC) - m * m;
    float rstd = rsqrtf(var + 1e-5f);
    out[row * cC + lane] = (v0 - m) * rstd * g[lane] + b[lane];
    if (lane < cC - 64)
        out[row * cC + lane + 64] = (v1 - m) * rstd * g[lane + 64] + b[lane + 64];
}

// ---------------- LDS-tiled fp32 GEMM: C = A(MxK)@B(KxN) [+bias][gelu][+res] ------
// block 256 threads -> BM=64 x BN=32 tile; thread -> 4 rows x 2 cols micro-tile
template <int ACT, bool HASB, bool HASR>
__global__ __launch_bounds__(256) void gemm_tile_kernel(
    const float* __restrict__ A, const float* __restrict__ B,
    const float* __restrict__ bias, const float* __restrict__ res,
    float* __restrict__ C, int M, int Nn, int Kk) {
    __shared__ float As[64][36];   // stride 36: conflict-free float4 reads
    __shared__ float Bs[32][32];
    int tid = threadIdx.x;
    int tx = tid & 15;             // 16 cols x 2
    int ty = tid >> 4;             // 16 rows x 4
    int row0 = blockIdx.y * 64;
    int n0 = blockIdx.x * 32;
    float acc[4][2] = {{0.f, 0.f}, {0.f, 0.f}, {0.f, 0.f}, {0.f, 0.f}};
    int nt = Kk >> 5;
    for (int kt = 0; kt < nt; kt++) {
#pragma unroll
        for (int t = 0; t < 2; t++) {
            int f = tid + t * 256;
            int ar = f >> 3, ac = (f & 7) * 4;
            const float4 v = *reinterpret_cast<const float4*>(
                A + (size_t)(row0 + ar) * Kk + kt * 32 + ac);
            *reinterpret_cast<float4*>(&As[ar][ac]) = v;
        }
        {
            int br = tid >> 3, bc = (tid & 7) * 4;
            const float4 v = *reinterpret_cast<const float4*>(
                B + (size_t)(kt * 32 + br) * Nn + n0 + bc);
            *reinterpret_cast<float4*>(&Bs[br][bc]) = v;
        }
        __syncthreads();
#pragma unroll
        for (int k4 = 0; k4 < 8; k4++) {
            float4 a0 = *reinterpret_cast<float4*>(&As[ty * 4 + 0][k4 * 4]);
            float4 a1 = *reinterpret_cast<float4*>(&As[ty * 4 + 1][k4 * 4]);
            float4 a2 = *reinterpret_cast<float4*>(&As[ty * 4 + 2][k4 * 4]);
            float4 a3 = *reinterpret_cast<float4*>(&As[ty * 4 + 3][k4 * 4]);
            float2 b0 = *reinterpret_cast<float2*>(&Bs[k4 * 4 + 0][tx * 2]);
            float2 b1 = *reinterpret_cast<float2*>(&Bs[k4 * 4 + 1][tx * 2]);
            float2 b2 = *reinterpret_cast<float2*>(&Bs[k4 * 4 + 2][tx * 2]);
            float2 b3 = *reinterpret_cast<float2*>(&Bs[k4 * 4 + 3][tx * 2]);
            acc[0][0] = fmaf(a0.x, b0.x, acc[0][0]); acc[0][1] = fmaf(a0.x, b0.y, acc[0][1]);
            acc[1][0] = fmaf(a1.x, b0.x, acc[1][0]); acc[1][1] = fmaf(a1.x, b0.y, acc[1][1]);
            acc[2][0] = fmaf(a2.x, b0.x, acc[2][0]); acc[2][1] = fmaf(a2.x, b0.y, acc[2][1]);
            acc[3][0] = fmaf(a3.x, b0.x, acc[3][0]); acc[3][1] = fmaf(a3.x, b0.y, acc[3][1]);
            acc[0][0] = fmaf(a0.y, b1.x, acc[0][0]); acc[0][1] = fmaf(a0.y, b1.y, acc[0][1]);
            acc[1][0] = fmaf(a1.y, b1.x, acc[1][0]); acc[1][1] = fmaf(a1.y, b1.y, acc[1][1]);
            acc[2][0] = fmaf(a2.y, b1.x, acc[2][0]); acc[2][1] = fmaf(a2.y, b1.y, acc[2][1]);
            acc[3][0] = fmaf(a3.y, b1.x, acc[3][0]); acc[3][1] = fmaf(a3.y, b1.y, acc[3][1]);
            acc[0][0] = fmaf(a0.z, b2.x, acc[0][0]); acc[0][1] = fmaf(a0.z, b2.y, acc[0][1]);
            acc[1][0] = fmaf(a1.z, b2.x, acc[1][0]); acc[1][1] = fmaf(a1.z, b2.y, acc[1][1]);
            acc[2][0] = fmaf(a2.z, b2.x, acc[2][0]); acc[2][1] = fmaf(a2.z, b2.y, acc[2][1]);
            acc[3][0] = fmaf(a3.z, b2.x, acc[3][0]); acc[3][1] = fmaf(a3.z, b2.y, acc[3][1]);
            acc[0][0] = fmaf(a0.w, b3.x, acc[0][0]); acc[0][1] = fmaf(a0.w, b3.y, acc[0][1]);
            acc[1][0] = fmaf(a1.w, b3.x, acc[1][0]); acc[1][1] = fmaf(a1.w, b3.y, acc[1][1]);
            acc[2][0] = fmaf(a2.w, b3.x, acc[2][0]); acc[2][1] = fmaf(a2.w, b3.y, acc[2][1]);
            acc[3][0] = fmaf(a3.w, b3.x, acc[3][0]); acc[3][1] = fmaf(a3.w, b3.y, acc[3][1]);
        }
        __syncthreads();
    }
    int cc = n0 + tx * 2;
    float bx_ = 0.f, by_ = 0.f;
    if (HASB) { bx_ = bias[cc]; by_ = bias[cc + 1]; }
#pragma unroll
    for (int i = 0; i < 4; i++) {
        int rr = row0 + ty * 4 + i;
        float v0 = acc[i][0], v1 = acc[i][1];
        if (HASB) { v0 += bx_; v1 += by_; }
        if (ACT == 1) { v0 = geluf(v0); v1 = geluf(v1); }
        if (HASR) {
            const float2 r2 = *reinterpret_cast<const float2*>(res + (size_t)rr * Nn + cc);
            v0 += r2.x; v1 += r2.y;
        }
        float2 o; o.x = v0; o.y = v1;
        *reinterpret_cast<float2*>(C + (size_t)rr * Nn + cc) = o;
    }
}

// ---------------- depthwise 3x3 conv + bias + silu ----------------
__global__ void conv_silu_kernel(const float* __restrict__ xz, const float* __restrict__ cw,
                                 const float* __restrict__ cb, float* __restrict__ out) {
    int idx = blockIdx.x * 256 + threadIdx.x;
    if (idx >= cL * cDI) return;
    int d = idx % cDI;
    int l = idx / cDI;
    int h = l / cW, w = l % cW;
    float s = cb[d];
#pragma unroll
    for (int dh = 0; dh < 3; dh++) {
        int hh = h + dh - 1;
        if (hh < 0 || hh >= cH) continue;
#pragma unroll
        for (int dw = 0; dw < 3; dw++) {
            int w2 = w + dw - 1;
            if (w2 < 0 || w2 >= cW) continue;
            s = fmaf(xz[(size_t)(hh * cW + w2) * (2 * cDI) + d], cw[(dh * 3 + dw) * cDI + d], s);
        }
    }
    out[idx] = siluf(s);
}

// ---------------- x_proj + dt_proj; outputs stored in SCAN order j ----------------
__global__ void proj_kernel(const float* __restrict__ xconv, const float* __restrict__ xpw,
                            const float* __restrict__ dtw, const float* __restrict__ dtb,
                            float* __restrict__ dtout, float* __restrict__ Bsout,
                            float* __restrict__ Csout) {
    __shared__ float XS[16 * 193];
    __shared__ float DTS[6 * 16];
    int k = blockIdx.y;
    int p0 = blockIdx.x * 16;
    int tid = threadIdx.x;
    for (int idx = tid; idx < 16 * cDI; idx += 256) {
        int p = idx / cDI, d = idx % cDI;
        int j = p0 + p;
        int jj = (k >= 2) ? (cL - 1 - j) : j;
        int rrow = (k & 1) ? ((jj % cH) * cW + (jj / cH)) : jj;
        XS[p * 193 + d] = xconv[(size_t)rrow * cDI + d];
    }
    __syncthreads();
    for (int o = tid; o < 38 * 16; o += 256) {
        int c = o >> 4, p = o & 15;
        const float* wr = xpw + (size_t)(k * 38 + c) * cDI;
        const float* xr = XS + p * 193;
        float s = 0.f;
#pragma unroll 4
        for (int d = 0; d < cDI; d++) s = fmaf(wr[d], xr[d], s);
        if (c < 6) DTS[c * 16 + p] = s;
        else if (c < 22) Bsout[(size_t)(k * cL + p0 + p) * cN + (c - 6)] = s;
        else Csout[(size_t)(k * cL + p0 + p) * cN + (c - 22)] = s;
    }
    __syncthreads();
    for (int o = tid; o < cDI * 16; o += 256) {
        int d = o >> 4, p = o & 15;
        float s = dtb[k * cDI + d];
        const float* wr = dtw + (size_t)(k * cDI + d) * cDR;
#pragma unroll
        for (int r = 0; r < cDR; r++) s = fmaf(wr[r], DTS[r * 16 + p], s);
        float sp = (s > 20.f) ? s : log1pf(expf(s));
        dtout[(size_t)(k * cDI + d) * cL + p0 + p] = sp;
    }
}

// physical-row walker for direction k at scan index j
__device__ __forceinline__ void walker_init(int k, int j0, int& r, int& dr) {
    if (k == 0) { r = j0; dr = 1; }
    else if (k == 1) { r = (j0 % cH) * cW + (j0 / cH); dr = cW; }
    else if (k == 2) { r = cL - 1 - j0; dr = -1; }
    else { int jp = cL - 1 - j0; r = (jp % cH) * cW + (jp / cH); dr = -cW; }
}
__device__ __forceinline__ void walker_step(int& r, int dr) {
    r += dr;
    if (r >= cL) r -= cL - 1;
    else if (r < 0) r += cL - 1;
}

// ---------------- scan pass 1 ----------------
__global__ void scan1_kernel(const float* __restrict__ dtbuf, const float* __restrict__ Bs,
                             const float* __restrict__ xconv, const float* __restrict__ Alogs,
                             float* __restrict__ carryP, float* __restrict__ carryH) {
    int bx = blockIdx.x;
    int c = bx % cNC;
    int t2 = bx / cNC;
    int d0 = (t2 % (cDI / 16)) * 16;
    int k = t2 / (cDI / 16);
    int g = threadIdx.x >> 4;
    int n = threadIdx.x & 15;
    int d = d0 + g;
    int kd = k * cDI + d;
    float An2 = -expf(Alogs[kd * cN + n]) * LOG2E;
    int j0 = c * cCH;
    int r, dr;
    walker_init(k, j0, r, dr);
    const float* dtp = dtbuf + (size_t)kd * cL;
    const float* bsp = Bs + (size_t)k * cL * cN + n;
    float h = 0.f, S = 0.f;
    for (int i = 0; i < cCH; i += 4) {
        int j = j0 + i;
        const float4 dt4 = *reinterpret_cast<const float4*>(dtp + j);
        float xv0 = xconv[r * cDI + d]; walker_step(r, dr);
        float xv1 = xconv[r * cDI + d]; walker_step(r, dr);
        float xv2 = xconv[r * cDI + d]; walker_step(r, dr);
        float xv3 = xconv[r * cDI + d]; walker_step(r, dr);
        float bv0 = bsp[(size_t)(j + 0) * cN];
        float bv1 = bsp[(size_t)(j + 1) * cN];
        float bv2 = bsp[(size_t)(j + 2) * cN];
        float bv3 = bsp[(size_t)(j + 3) * cN];
        float a0 = fast_exp2(An2 * dt4.x);
        float a1 = fast_exp2(An2 * dt4.y);
        float a2 = fast_exp2(An2 * dt4.z);
        float a3 = fast_exp2(An2 * dt4.w);
        h = fmaf(a0, h, dt4.x * bv0 * xv0);
        h = fmaf(a1, h, dt4.y * bv1 * xv1);
        h = fmaf(a2, h, dt4.z * bv2 * xv2);
        h = fmaf(a3, h, dt4.w * bv3 * xv3);
        S += dt4.x + dt4.y + dt4.z + dt4.w;
    }
    float P = fast_exp2(An2 * S);
    int idxc = (kd * cNC + c) * cN + n;
    carryH[idxc] = h;
    carryP[idxc] = P;
}

// ---------------- scan pass 2 ----------------
__global__ void scan2_kernel(const float* __restrict__ carryP, const float* __restrict__ carryH,
                             float* __restrict__ hin) {
    int gid = blockIdx.x * 256 + threadIdx.x;
    if (gid >= cK * cDI * cN) return;
    int kd = gid / cN, n = gid % cN;
    float h = 0.f;
    for (int c = 0; c < cNC; c++) {
        int idxc = (kd * cNC + c) * cN + n;
        hin[idxc] = h;
        h = fmaf(carryP[idxc], h, carryH[idxc]);
    }
}

// ---------------- scan pass 3 ----------------
__global__ void scan3_kernel(const float* __restrict__ dtbuf, const float* __restrict__ Bs,
                             const float* __restrict__ Cs, const float* __restrict__ xconv,
                             const float* __restrict__ Alogs, const float* __restrict__ Ds,
                             const float* __restrict__ hin, float* __restrict__ ysS) {
    int bx = blockIdx.x;
    int c = bx % cNC;
    int t2 = bx / cNC;
    int d0 = (t2 % (cDI / 16)) * 16;
    int k = t2 / (cDI / 16);
    int g = threadIdx.x >> 4;
    int n = threadIdx.x & 15;
    int d = d0 + g;
    int kd = k * cDI + d;
    float An2 = -expf(Alogs[kd * cN + n]) * LOG2E;
    float Dv = Ds[kd];
    int j0 = c * cCH;
    int r, dr;
    walker_init(k, j0, r, dr);
    const float* dtp = dtbuf + (size_t)kd * cL;
    const float* bsp = Bs + (size_t)k * cL * cN + n;
    const float* csp = Cs + (size_t)k * cL * cN + n;
    float h = hin[(kd * cNC + c) * cN + n];
    for (int i = 0; i < cCH; i += 4) {
        int j = j0 + i;
        const float4 dt4 = *reinterpret_cast<const float4*>(dtp + j);
        float xv0 = xconv[r * cDI + d]; walker_step(r, dr);
        float xv1 = xconv[r * cDI + d]; walker_step(r, dr);
        float xv2 = xconv[r * cDI + d]; walker_step(r, dr);
        float xv3 = xconv[r * cDI + d]; walker_step(r, dr);
        float bv0 = bsp[(size_t)(j + 0) * cN];
        float bv1 = bsp[(size_t)(j + 1) * cN];
        float bv2 = bsp[(size_t)(j + 2) * cN];
        float bv3 = bsp[(size_t)(j + 3) * cN];
        float cv0 = csp[(size_t)(j + 0) * cN];
        float cv1 = csp[(size_t)(j + 1) * cN];
        float cv2 = csp[(size_t)(j + 2) * cN];
        float cv3 = csp[(size_t)(j + 3) * cN];
        float a0 = fast_exp2(An2 * dt4.x);
        float a1 = fast_exp2(An2 * dt4.y);
        float a2 = fast_exp2(An2 * dt4.z);
        float a3 = fast_exp2(An2 * dt4.w);
        h = fmaf(a0, h, dt4.x * bv0 * xv0);
        float t0 = dpp_red16(h * cv0);
        h = fmaf(a1, h, dt4.y * bv1 * xv1);
        float t1 = dpp_red16(h * cv1);
        h = fmaf(a2, h, dt4.z * bv2 * xv2);
        float t2v = dpp_red16(h * cv2);
        h = fmaf(a3, h, dt4.w * bv3 * xv3);
        float t3 = dpp_red16(h * cv3);
        if (n == 0) {
            ysS[(size_t)(k * cL + j + 0) * cDI + d] = t0 + Dv * xv0;
            ysS[(size_t)(k * cL + j + 1) * cDI + d] = t1 + Dv * xv1;
            ysS[(size_t)(k * cL + j + 2) * cDI + d] = t2v + Dv * xv2;
            ysS[(size_t)(k * cL + j + 3) * cDI + d] = t3 + Dv * xv3;
        }
    }
}

// ---------------- combine 4 directions + out-LN + silu(z) ----------------
__global__ void lnout_kernel(const float* __restrict__ ysS, const float* __restrict__ xz,
                             const float* __restrict__ g, const float* __restrict__ b,
                             float* __restrict__ ymul) {
    int wid = threadIdx.x >> 6, lane = threadIdx.x & 63;
    int l = blockIdx.x * 4 + wid;
    if (l >= cL) return;
    int h_ = l / cW, w_ = l % cW;
    int lc = w_ * cH + h_;
    float v[3];
    float s = 0.f, sq = 0.f;
#pragma unroll
    for (int j = 0; j < 3; j++) {
        int d = lane + j * 64;
        float t = ysS[(size_t)(0 * cL + l) * cDI + d] +
                  ysS[(size_t)(1 * cL + lc) * cDI + d] +
                  ysS[(size_t)(2 * cL + (cL - 1 - l)) * cDI + d] +
                  ysS[(size_t)(3 * cL + (cL - 1 - lc)) * cDI + d];
        v[j] = t;
        s += t;
        sq += t * t;
    }
#pragma unroll
    for (int off = 32; off; off >>= 1) {
        s += __shfl_xor(s, off, 64);
        sq += __shfl_xor(sq, off, 64);
    }
    float m = s * (1.f / cDI);
    float var = sq * (1.f / cDI) - m * m;
    float rstd = rsqrtf(var + 1e-5f);
#pragma unroll
    for (int j = 0; j < 3; j++) {
        int d = lane + j * 64;
        float z = xz[(size_t)l * (2 * cDI) + cDI + d];
        ymul[(size_t)l * cDI + d] = ((v[j] - m) * rstd * g[d] + b[d]) * siluf(z);
    }
}

extern "C" void kernel_launch(void* const* d_in, const int* in_sizes, int n_in,
                              void* d_out, int out_size, void* d_ws, size_t ws_size,
                              hipStream_t stream) {
    const float* x         = (const float*)d_in[0];
    const float* norm_g    = (const float*)d_in[1];
    const float* norm_b    = (const float*)d_in[2];
    const float* in_proj_w = (const float*)d_in[3];
    const float* conv_w    = (const float*)d_in[4];
    const float* conv_b    = (const float*)d_in[5];
    const float* x_proj_w  = (const float*)d_in[6];
    const float* dt_projs_w= (const float*)d_in[7];
    const float* dt_projs_b= (const float*)d_in[8];
    const float* A_logs    = (const float*)d_in[9];
    const float* Ds        = (const float*)d_in[10];
    const float* out_norm_g= (const float*)d_in[11];
    const float* out_norm_b= (const float*)d_in[12];
    const float* out_proj_w= (const float*)d_in[13];
    const float* norm2_g   = (const float*)d_in[14];
    const float* norm2_b   = (const float*)d_in[15];
    const float* fc1_w     = (const float*)d_in[16];
    const float* fc1_b     = (const float*)d_in[17];
    const float* fc2_w     = (const float*)d_in[18];
    const float* fc2_b     = (const float*)d_in[19];

    float* ws = (float*)d_ws;
    float* ln_buf = ws;                    // 301056
    float* xz     = ws + 301056;           // 1204224
    float* xconv  = ws + 1505280;          // 602112 (ymul aliases after scan3)
    float* dtb_   = ws + 2107392;          // 2408448  [k][d][j] scan order
    float* Bs     = ws + 4515840;          // 200704   [k][j][n] scan order
    float* Cs     = ws + 4716544;          // 200704   [k][j][n] scan order
    float* hin    = ws + 4917248;          // 602112
    float* ysS    = ws + 5519360;          // 2408448  [k][j][d] scan order
    float* cP     = ysS;                   // 602112 (dead before scan3 writes)
    float* cHh    = ysS + 602112;          // 602112
    float* ymul   = xconv;                 // reuse xconv (dead after scan3)
    float* x1     = ws + 7927808;          // 301056
    float* hm     = xz;                    // reuse xz for MLP hidden
    float* out    = (float*)d_out;

    // 1. LN1
    ln96_kernel<<<cL / 4, 256, 0, stream>>>(x, norm_g, norm_b, ln_buf, cL);
    // 2. in_proj GEMM (L,96)@(96,384)
    gemm_tile_kernel<0, false, false><<<dim3(384 / 32, cL / 64), 256, 0, stream>>>(
        ln_buf, in_proj_w, nullptr, nullptr, xz, cL, 2 * cDI, cC);
    // 3. depthwise conv + silu
    conv_silu_kernel<<<(cL * cDI) / 256, 256, 0, stream>>>(xz, conv_w, conv_b, xconv);
    // 4. x_proj + dt_proj (scan-order outputs)
    proj_kernel<<<dim3(cL / 16, cK), 256, 0, stream>>>(xconv, x_proj_w, dt_projs_w,
                                                       dt_projs_b, dtb_, Bs, Cs);
    // 5-7. chunked scan
    scan1_kernel<<<cK * (cDI / 16) * cNC, 256, 0, stream>>>(dtb_, Bs, xconv, A_logs, cP, cHh);
    scan2_kernel<<<(cK * cDI * cN + 255) / 256, 256, 0, stream>>>(cP, cHh, hin);
    scan3_kernel<<<cK * (cDI / 16) * cNC, 256, 0, stream>>>(dtb_, Bs, Cs, xconv, A_logs, Ds,
                                                            hin, ysS);
    // 8. combine + out LN + silu(z)
    lnout_kernel<<<cL / 4, 256, 0, stream>>>(ysS, xz, out_norm_g, out_norm_b, ymul);
    // 9. out_proj + residual (L,192)@(192,96)
    gemm_tile_kernel<0, false, true><<<dim3(96 / 32, cL / 64), 256, 0, stream>>>(
        ymul, out_proj_w, nullptr, x, x1, cL, cC, cDI);
    // 10. LN2
    ln96_kernel<<<cL / 4, 256, 0, stream>>>(x1, norm2_g, norm2_b, ln_buf, cL);
    // 11. fc1 + bias + gelu (L,96)@(96,384)
    gemm_tile_kernel<1, true, false><<<dim3(384 / 32, cL / 64), 256, 0, stream>>>(
        ln_buf, fc1_w, fc1_b, nullptr, hm, cL, cMH, cC);
    // 12. fc2 + bias + residual (L,384)@(384,96)
    gemm_tile_kernel<0, true, true><<<dim3(96 / 32, cL / 64), 256, 0, stream>>>(
        hm, fc2_w, fc2_b, x1, out, cL, cC, cMH);
}